// Round 7
// baseline (333.008 us; speedup 1.0000x reference)
//
#include <hip/hip_runtime.h>

// EfficientHebbian on MI355X (gfx950) — round 10.
// r9 result: kperm'd operands -> bank conflicts 0. Remaining big-GEMM limit:
// DEPTH=2 ring has zero lookahead (steady waitvm(0)) and HW runs ~1 blk/CU.
// r10: big GEMMs -> 8 waves (2x4), DEPTH=4, 128KB LDS, steady waitvm(8)
// (2 stages always in flight, never drained). Small GEMMs unchanged
// (DEPTH=8,U=2,128KB, proven). pinit folded into cvt.

typedef short short4v __attribute__((ext_vector_type(4)));
typedef short short8v __attribute__((ext_vector_type(8)));
typedef unsigned short ushort4v __attribute__((ext_vector_type(4)));
typedef unsigned short ushort8v __attribute__((ext_vector_type(8)));
typedef float f32x4 __attribute__((ext_vector_type(4)));

__device__ __forceinline__ unsigned short f2bf(float f) {
  union { float f; unsigned u; } v; v.f = f;
  unsigned r = 0x7fffu + ((v.u >> 16) & 1u);
  return (unsigned short)((v.u + r) >> 16);
}

// k-permutation within a 64-element group: natural k -> stored position.
// Stored 16B chunk c=(ks*4+g) holds natural {ks*32+g*4+[0,4), ks*32+g*4+16+[0,4)}
// = exactly one mfma_16x16x32 bf16 fragment per lane.
__device__ __forceinline__ int kperm(int t) {
  return (t & 32) + ((t >> 2) & 3) * 8 + ((t >> 4) & 1) * 4 + (t & 3);
}

__device__ __forceinline__ void gload_lds16(const void* g, void* l) {
  __builtin_amdgcn_global_load_lds(
      (const __attribute__((address_space(1))) void*)g,
      (__attribute__((address_space(3))) void*)l, 16, 0, 0);
}

// counted vmcnt wait; "memory" clobber = compiler fence for LDS/VMEM motion
__device__ __forceinline__ void waitvm(int n) {
  switch (n) {
    case 0: asm volatile("s_waitcnt vmcnt(0)" ::: "memory"); break;
    case 2: asm volatile("s_waitcnt vmcnt(2)" ::: "memory"); break;
    case 4: asm volatile("s_waitcnt vmcnt(4)" ::: "memory"); break;
    case 6: asm volatile("s_waitcnt vmcnt(6)" ::: "memory"); break;
    case 8: asm volatile("s_waitcnt vmcnt(8)" ::: "memory"); break;
    case 10: asm volatile("s_waitcnt vmcnt(10)" ::: "memory"); break;
    case 12: asm volatile("s_waitcnt vmcnt(12)" ::: "memory"); break;
    default: asm volatile("s_waitcnt vmcnt(0)" ::: "memory"); break;
  }
}

// ---------------- LayerNorm: x[row][1024] f32 -> xn bf16 (kperm'd) ----------
__global__ void __launch_bounds__(256) ln_kernel(
    const float* __restrict__ x, const float* __restrict__ gamma,
    const float* __restrict__ beta, unsigned short* __restrict__ xn) {
  __shared__ float sb[4];
  const int row = blockIdx.x;
  const int t = threadIdx.x;
  const float* xr = x + (size_t)row * 1024;
  f32x4 v = *(const f32x4*)(xr + t * 4);
  float s = v[0] + v[1] + v[2] + v[3];
  for (int m = 32; m; m >>= 1) s += __shfl_xor(s, m);
  if ((t & 63) == 0) sb[t >> 6] = s;
  __syncthreads();
  float mu = (sb[0] + sb[1] + sb[2] + sb[3]) * (1.0f / 1024.0f);
  __syncthreads();
  f32x4 d; float q = 0.f;
  for (int i = 0; i < 4; i++) { d[i] = v[i] - mu; q += d[i] * d[i]; }
  for (int m = 32; m; m >>= 1) q += __shfl_xor(q, m);
  if ((t & 63) == 0) sb[t >> 6] = q;
  __syncthreads();
  float var = (sb[0] + sb[1] + sb[2] + sb[3]) * (1.0f / 1024.0f);
  float rs = rsqrtf(var + 1e-5f);
  f32x4 g4 = *(const f32x4*)(gamma + t * 4);
  f32x4 b4 = *(const f32x4*)(beta + t * 4);
  ushort4v o;
  for (int i = 0; i < 4; i++) o[i] = f2bf(d[i] * rs * g4[i] + b4[i]);
  int col = t * 4;
  int sc = (col & ~63) + kperm(col & 63);
  *(ushort4v*)(xn + (size_t)row * 1024 + sc) = o;
}

// ------- f32 -> bf16 convert (kperm'd); block 0 zeroes colsumsq;
// ------- block 1 does power-iteration v0 init + zeroes norms (was pinit) ----
__global__ void __launch_bounds__(256) cvt_kernel(
    const float* __restrict__ in, unsigned short* __restrict__ out,
    float* __restrict__ zbuf, float* __restrict__ v0,
    float* __restrict__ norms) {
  if (blockIdx.x == 0) {
    f32x4 z = (f32x4){0.f, 0.f, 0.f, 0.f};
    ((f32x4*)zbuf)[threadIdx.x] = z;
  } else if (blockIdx.x == 1) {
    int t = threadIdx.x;
    for (int q = 0; q < 4; q++) {
      int i = t * 4 + q;
      unsigned h = (unsigned)i * 2654435761u;
      v0[i] = ((h >> 16) & 1u) ? 1.f : -1.f;
    }
    if (t < 4) norms[t] = 0.f;
  }
  size_t e = ((size_t)blockIdx.x * 256 + threadIdx.x) * 4;
  f32x4 v = *(const f32x4*)(in + e);
  ushort4v o;
  for (int k = 0; k < 4; k++) o[k] = f2bf(v[k]);
  int col = (int)(e & 1023);
  size_t sp = (e & ~(size_t)1023) + (col & ~63) + kperm(col & 63);
  *(ushort4v*)(out + sp) = o;
}

// -- bf16 transpose 64x64 tiles: in kperm'd rows -> out kperm'd rows ----------
__global__ void __launch_bounds__(256) transpose_kernel(
    const unsigned short* __restrict__ in, unsigned short* __restrict__ out,
    int R, int C) {
  __shared__ unsigned short tb[64][65];
  const int t = threadIdx.x;
  const int r0 = blockIdx.x * 64, c0 = blockIdx.y * 64;
#pragma unroll
  for (int p = 0; p < 2; p++) {
    int lr = p * 32 + (t >> 3);
    int lc = (t & 7) * 8;  // stored position within 64-group
    ushort8v v = *(const ushort8v*)(in + (size_t)(r0 + lr) * C + c0 + lc);
    int ch = lc >> 3;                         // stored chunk index
    int nb = (ch >> 2) * 32 + (ch & 3) * 4;   // natural base
#pragma unroll
    for (int d = 0; d < 4; d++) tb[lr][nb + d] = v[d];
#pragma unroll
    for (int d = 4; d < 8; d++) tb[lr][nb + 16 + d - 4] = v[d];
  }
  __syncthreads();
#pragma unroll
  for (int p = 0; p < 2; p++) {
    int orr = p * 32 + (t >> 3);
    int oc = (t & 7) * 8;  // natural token offset
    ushort4v w0, w1;
#pragma unroll
    for (int d = 0; d < 4; d++) { w0[d] = tb[oc + d][orr]; w1[d] = tb[oc + 4 + d][orr]; }
    unsigned short* orow = out + (size_t)(c0 + orr) * R + r0;
    *(ushort4v*)(orow + kperm(oc)) = w0;
    *(ushort4v*)(orow + kperm(oc + 4)) = w1;
  }
}

// ---------------- NT GEMM: C[M][N] = A[M][K] @ B[N][K]^T ----------------
// Operands stored kperm'd; fragment read = single ds_read_b128, conflict-free.
// BM x BM tile, BK=64, NK=16 K-steps, WM x WN waves. DEPTH-buffer ring,
// raw s_barrier + counted vmcnt, U tiles per barrier window.
// modes: 0: v=acc (+addF) ; 1: c0*I+c1*addF+c2*acc ; 2: dcoef variant
//        3: 0.9*addF + (1/32)*(acc + addF2*dvec[c])
//        5: symmetric-upper partial, XCD-slab map (flat 576 grid)
//        6: mode 0 with flat-grid XCD swizzle (M=128,N=8 tiles)
template <int BM, int WM, int WN, int DEPTH, int U>
__global__ void __launch_bounds__(WM * WN * 64, 2) gemm_bt_kernel(
    const unsigned short* __restrict__ A, const unsigned short* __restrict__ B,
    const float* __restrict__ addF, const float* __restrict__ addF2,
    const float* __restrict__ dvec, const float* __restrict__ dcoef,
    float* __restrict__ outF, unsigned short* __restrict__ outB,
    unsigned short* __restrict__ outBT,
    int ldk, int Kseg, int mode, float c0, float c1, float c2) {
  constexpr int WAVES = WM * WN;
  constexpr int NT = WAVES * 64;
  constexpr int FMm = BM / (16 * WM);
  constexpr int FMn = BM / (16 * WN);
  constexpr int CPW = BM / (8 * WAVES);  // 1KB chunks per wave per operand
  constexpr int L = 2 * CPW;             // vmem loads per wave per stage
  constexpr int BUFS = 2 * BM * 64;      // shorts per buffer (A then B)
  constexpr int NK = 16;                 // Kseg == 1024 always
  constexpr int NG = NK / U;
  __shared__ __align__(16) unsigned short lds[DEPTH * BUFS];
  const int tid = threadIdx.x, lane = tid & 63, wv = tid >> 6;
  const int wm = wv / WN, wn = wv % WN;

  int m0, n0, kb = 0, zseg = 0;
  if (mode == 5) {
    int id = blockIdx.x;
    int c = id & 7, s = id >> 3;
    zseg = c * 2 + (s >= 36 ? 1 : 0);
    int tt = (s >= 36) ? s - 36 : s;
    int ti = 0;
    while (tt >= 8 - ti) { tt -= 8 - ti; ++ti; }
    m0 = ti * BM; n0 = (ti + tt) * BM;
    kb = zseg * Kseg;
  } else if (mode == 6) {
    int l = blockIdx.x;
    int c = l & 7, s = l >> 3;
    m0 = (c * 16 + (s >> 3)) * BM;
    n0 = (s & 7) * BM;
  } else {
    m0 = blockIdx.x * BM; n0 = blockIdx.y * BM;
  }

  const int srow = lane >> 3;
  const int skoff = 8 * ((lane & 7) ^ srow);  // pre-swizzled global k-offset

  f32x4 acc[FMm][FMn];
  for (int a = 0; a < FMm; a++)
    for (int b = 0; b < FMn; b++) acc[a][b] = (f32x4){0.f, 0.f, 0.f, 0.f};

  auto stage = [&](int buf, int kk) {
#pragma unroll
    for (int ci = 0; ci < CPW; ci++) {
      int ch = wv * CPW + ci;
      const unsigned short* ga = A + (size_t)(m0 + 8 * ch + srow) * ldk + kk + skoff;
      const unsigned short* gb = B + (size_t)(n0 + 8 * ch + srow) * ldk + kk + skoff;
      char* lb = (char*)(lds + buf * BUFS);
      gload_lds16(ga, lb + ch * 1024);
      gload_lds16(gb, lb + BM * 128 + ch * 1024);
    }
  };

  // prologue: DEPTH-U stages in flight
#pragma unroll
  for (int d = 0; d < DEPTH - U; ++d) stage(d, kb + (d << 6));

#pragma unroll
  for (int g = 0; g < NG; ++g) {
    int done = U * g + U;                       // tiles that must be complete
    int issued = DEPTH - U + U * g;
    if (issued > NK) issued = NK;
    int ahead = issued - done;                  // stages allowed in flight
    waitvm(ahead * L);
    __builtin_amdgcn_s_barrier();
#pragma unroll
    for (int u = 0; u < U; ++u) {
      int ts = U * g + (DEPTH - U) + u;
      if (ts < NK) stage(ts % DEPTH, kb + (ts << 6));
    }

    const int g16 = lane >> 4;
#pragma unroll
    for (int u = 0; u < U; ++u) {
      const unsigned short* As = lds + ((U * g + u) % DEPTH) * BUFS;
      const unsigned short* Bs = As + BM * 64;
#pragma unroll
      for (int ks = 0; ks < 2; ks++) {
        short8v af[FMm], bfr[FMn];
        const int slot = (ks * 4 + g16) * 16;   // 16B chunk = full fragment
#pragma unroll
        for (int fm = 0; fm < FMm; fm++) {
          int row = wm * (BM / WM) + fm * 16 + (lane & 15);
          int swz = (row & 7) << 4;
          af[fm] = *(const short8v*)((const char*)As + row * 128 + (slot ^ swz));
        }
#pragma unroll
        for (int fn = 0; fn < FMn; fn++) {
          int row = wn * (BM / WN) + fn * 16 + (lane & 15);
          int swz = (row & 7) << 4;
          bfr[fn] = *(const short8v*)((const char*)Bs + row * 128 + (slot ^ swz));
        }
#pragma unroll
        for (int fm = 0; fm < FMm; fm++)
#pragma unroll
          for (int fn = 0; fn < FMn; fn++)
            acc[fm][fn] = __builtin_amdgcn_mfma_f32_16x16x32_bf16(
                af[fm], bfr[fn], acc[fm][fn], 0, 0, 0);
      }
    }
  }

  float* of = outF;
  if (mode == 5 && of) of += ((size_t)zseg << 20);
  float dc0 = 0.f, dc1 = 0.f, dc2 = 0.f;
  if (mode == 2) { dc0 = dcoef[0]; dc1 = dcoef[1]; dc2 = dcoef[2]; }

#pragma unroll
  for (int fm = 0; fm < FMm; fm++) {
    int r0 = m0 + wm * (BM / WM) + fm * 16 + (lane >> 4) * 4;
#pragma unroll
    for (int fn = 0; fn < FMn; fn++) {
      int c = n0 + wn * (BM / WN) + fn * 16 + (lane & 15);
      int cperm = (c & ~63) + kperm(c & 63);    // stored col for bf16 out
#pragma unroll
      for (int j = 0; j < 4; j++) {
        int r = r0 + j;
        size_t off = (size_t)r * 1024 + c;
        float v = acc[fm][fn][j];
        if (mode == 0 || mode == 6) {
          if (addF) v += addF[off];
        } else if (mode == 1) {
          v = c0 * (r == c ? 1.f : 0.f) + (addF ? c1 * addF[off] : 0.f) + c2 * v;
        } else if (mode == 2) {
          v = dc0 * (r == c ? 1.f : 0.f) + dc1 * addF[off] + dc2 * v;
        } else if (mode == 3) {
          v = 0.9f * addF[off] + 0.03125f * (v + addF2[off] * dvec[c]);
        }
        if (of) of[off] = v;
        if (outB) outB[(size_t)r * 1024 + cperm] = f2bf(v);
        acc[fm][fn][j] = v;
      }
    }
  }

  // optional transposed bf16 output (BM=64 NS X-updates only), kperm'd k-dim
  if (outBT) {
    constexpr int LDT = BM + 1;
    __syncthreads();
#pragma unroll
    for (int fm = 0; fm < FMm; fm++) {
      int lr0 = wm * (BM / WM) + fm * 16 + (lane >> 4) * 4;
#pragma unroll
      for (int fn = 0; fn < FMn; fn++) {
        int lc = wn * (BM / WN) + fn * 16 + (lane & 15);
#pragma unroll
        for (int j = 0; j < 4; j++)
          lds[(lr0 + j) * LDT + lc] = f2bf(acc[fm][fn][j]);
      }
    }
    __syncthreads();
    for (int e = tid * 8; e < BM * BM; e += NT * 8) {
      int orr = e / BM;          // output row = col of tile
      int oc = e % BM;           // natural k offset (row of tile), mult of 8
      ushort4v w0, w1;
#pragma unroll
      for (int d = 0; d < 4; d++) {
        w0[d] = lds[(oc + d) * LDT + orr];
        w1[d] = lds[(oc + 4 + d) * LDT + orr];
      }
      unsigned short* orow = outBT + (size_t)(n0 + orr) * 1024 + m0;
      *(ushort4v*)(orow + kperm(oc & 63)) = w0;
      *(ushort4v*)(orow + kperm((oc + 4) & 63)) = w1;
    }
  }
}

// ---- reduce G: sum 16 partials over upper 128^2 tiles -> Gb bf16 (kperm'd),
// mirror lower triangle, diag zeroed + gdiag. grid: dim3(16, 36 tiles).
__global__ void __launch_bounds__(256) reduce_g_kernel(
    const float* __restrict__ P, unsigned short* __restrict__ Gb,
    float* __restrict__ gdiag) {
  int tt = blockIdx.y, ti = 0;
  while (tt >= 8 - ti) { tt -= 8 - ti; ++ti; }
  const int tj = ti + tt;
  const int eloc = (blockIdx.x * 256 + threadIdx.x) * 4;
  const int lr = eloc >> 7, lc = eloc & 127;
  const int r = ti * 128 + lr, c0 = tj * 128 + lc;
  const size_t off = (size_t)r * 1024 + c0;
  f32x4 s = *(const f32x4*)(P + off);
#pragma unroll
  for (int z = 1; z < 16; z++)
    s += *(const f32x4*)(P + ((size_t)z << 20) + off);
  ushort4v o;
  const int rperm = (r & ~63) + kperm(r & 63);
#pragma unroll
  for (int q = 0; q < 4; q++) {
    int c = c0 + q;
    unsigned short b = f2bf(s[q]);
    if (ti == tj && c == r) { gdiag[r] = s[q]; o[q] = 0; }
    else o[q] = b;
    if (ti != tj) Gb[(size_t)c * 1024 + rperm] = b;  // mirror (kperm'd col)
  }
  *(ushort4v*)(Gb + (size_t)r * 1024 + (c0 & ~63) + kperm(c0 & 63)) = o;
}

// --- w = weight + 0.01*clip(trace,-1,1); atomic per-column sumsq -------------
__global__ void __launch_bounds__(256) wbuild_kernel(
    const float* __restrict__ weight, const float* __restrict__ tout,
    float* __restrict__ w, float* __restrict__ colsumsq) {
  int t = threadIdx.x, blk = blockIdx.x;
  float cs[4] = {0.f, 0.f, 0.f, 0.f};
  for (int r = 0; r < 64; r++) {
    size_t row = (size_t)blk * 64 + r;
    for (int cc = 0; cc < 4; cc++) {
      size_t idx = row * 1024 + cc * 256 + t;
      float u = tout[idx];
      u = fminf(fmaxf(u, -1.f), 1.f);
      float wv = weight[idx] + 0.01f * u;
      w[idx] = wv;
      cs[cc] += wv * wv;
    }
  }
  for (int cc = 0; cc < 4; cc++) atomicAdd(&colsumsq[cc * 256 + t], cs[cc]);
}

// --- X0 = w / max(colnorm,1e-3): writes Xf (f32), Xb (bf16 kperm'd),
// XbT (bf16 kperm'd k-dim). tile-based 64x64.
__global__ void __launch_bounds__(256) x0t_kernel(
    const float* __restrict__ w, const float* __restrict__ colsumsq,
    float* __restrict__ X, unsigned short* __restrict__ Xb,
    unsigned short* __restrict__ XbT) {
  __shared__ unsigned short tb[64][65];
  const int t = threadIdx.x;
  const int r0 = blockIdx.x * 64, c0 = blockIdx.y * 64;
#pragma unroll
  for (int p = 0; p < 2; p++) {
    int lr = p * 32 + (t >> 3);
    int lc = (t & 7) * 8;  // natural col offset
    size_t base = (size_t)(r0 + lr) * 1024 + c0 + lc;
    f32x4 w0 = *(const f32x4*)(w + base);
    f32x4 w1 = *(const f32x4*)(w + base + 4);
    f32x4 s0 = *(const f32x4*)(colsumsq + c0 + lc);
    f32x4 s1 = *(const f32x4*)(colsumsq + c0 + lc + 4);
    f32x4 x0o, x1o; ushort4v xb0, xb1;
#pragma unroll
    for (int d = 0; d < 4; d++) {
      x0o[d] = w0[d] / fmaxf(sqrtf(s0[d]), 1e-3f);
      x1o[d] = w1[d] / fmaxf(sqrtf(s1[d]), 1e-3f);
      xb0[d] = f2bf(x0o[d]); xb1[d] = f2bf(x1o[d]);
      tb[lr][lc + d] = xb0[d]; tb[lr][lc + 4 + d] = xb1[d];
    }
    *(f32x4*)(X + base) = x0o;
    *(f32x4*)(X + base + 4) = x1o;
    unsigned short* xrow = Xb + (size_t)(r0 + lr) * 1024 + c0;
    *(ushort4v*)(xrow + kperm(lc)) = xb0;
    *(ushort4v*)(xrow + kperm(lc + 4)) = xb1;
  }
  __syncthreads();
#pragma unroll
  for (int p = 0; p < 2; p++) {
    int orr = p * 32 + (t >> 3);
    int oc = (t & 7) * 8;  // natural row offset (k-dim of XbT)
    ushort4v w0, w1;
#pragma unroll
    for (int d = 0; d < 4; d++) { w0[d] = tb[oc + d][orr]; w1[d] = tb[oc + 4 + d][orr]; }
    unsigned short* orow = XbT + (size_t)(c0 + orr) * 1024 + r0;
    *(ushort4v*)(orow + kperm(oc)) = w0;
    *(ushort4v*)(orow + kperm(oc + 4)) = w1;
  }
}

// ---------------- matvec: vout = A vin (A f32 1024x1024); ||vout||^2 += norm --
__global__ void __launch_bounds__(256) matvec_kernel(
    const float* __restrict__ A, const float* __restrict__ vin,
    float* __restrict__ vout, float* __restrict__ normsq) {
  __shared__ float red[4];
  int t = threadIdx.x;
  int r0 = blockIdx.x * 16;
  f32x4 vv = *(const f32x4*)(vin + t * 4);
  float sq = 0.f;
  for (int r = 0; r < 16; r++) {
    f32x4 a = *(const f32x4*)(A + (size_t)(r0 + r) * 1024 + t * 4);
    float d = a[0] * vv[0] + a[1] * vv[1] + a[2] * vv[2] + a[3] * vv[3];
    for (int m = 32; m; m >>= 1) d += __shfl_xor(d, m);
    if ((t & 63) == 0) red[t >> 6] = d;
    __syncthreads();
    if (t == 0) {
      float s = red[0] + red[1] + red[2] + red[3];
      vout[r0 + r] = s;
      sq += s * s;
    }
    __syncthreads();
  }
  if (t == 0) atomicAdd(normsq, sq);
}

// ---------------- quintic-1 coefficients from power-iter norms ----------------
__global__ void coefq_kernel(const float* __restrict__ norms,
                             float* __restrict__ dcoef) {
  const float QA = 3.4445f, QB = -4.7750f, QC = 2.0315f;
  float n1 = fmaxf(norms[1], 1e-30f), n2 = fmaxf(norms[2], 1e-30f);
  float lam = sqrtf(n2 / n1);            // ~ sigma_max^2
  float s = sqrtf(fmaxf(lam, 1e-8f)) / 0.95f;
  s = fmaxf(s, 1e-3f);
  float s2 = s * s;
  dcoef[0] = QA / s;
  dcoef[1] = QB / (s * s2);
  dcoef[2] = QC / (s * s2 * s2);
}

extern "C" void kernel_launch(void* const* d_in, const int* in_sizes, int n_in,
                              void* d_out, int out_size, void* d_ws, size_t ws_size,
                              hipStream_t stream) {
  const float* x      = (const float*)d_in[0];
  const float* weight = (const float*)d_in[1];
  const float* gamma  = (const float*)d_in[2];
  const float* beta   = (const float*)d_in[3];
  const float* trace  = (const float*)d_in[4];

  float* y_out = (float*)d_out;                  // [16384,1024]
  float* w_out = y_out + (size_t)16777216;       // [1024,1024]
  float* t_out = w_out + (size_t)1048576;        // [1024,1024]

  const size_t MB = 1048576;
  char* ws = (char*)d_ws;
  unsigned short* xn   = (unsigned short*)(ws);            // 32MB
  unsigned short* xnT  = (unsigned short*)(ws + 32 * MB);  // 32MB
  float* Xf0           = (float*)(ws + 64 * MB);           // 4MB
  float* Xf1           = (float*)(ws + 68 * MB);           // 4MB
  float* wbuf          = (float*)(ws + 72 * MB);           // 4MB (reused as Af)
  float* Af            = (float*)(ws + 72 * MB);           //   alias (wbuf dead)
  unsigned short* Xb0  = (unsigned short*)(ws + 76 * MB);  // 2MB
  unsigned short* Xb1  = (unsigned short*)(ws + 78 * MB);  // 2MB
  unsigned short* XbT0 = (unsigned short*)(ws + 80 * MB);  // 2MB
  unsigned short* XbT1 = (unsigned short*)(ws + 82 * MB);  // 2MB
  unsigned short* Ab   = (unsigned short*)(ws + 84 * MB);  // 2MB
  unsigned short* Rb   = (unsigned short*)(ws + 86 * MB);  // 2MB (also quintic B)
  unsigned short* Gb   = (unsigned short*)(ws + 88 * MB);  // 2MB
  unsigned short* wb   = (unsigned short*)(ws + 90 * MB);  // 2MB
  float* colsumsq      = (float*)(ws + 92 * MB);           // 4KB
  float* gdiag         = (float*)(ws + 92 * MB + 69632);   // 4KB
  float* vpow          = (float*)(ws + 92 * MB + 73728);   // 4 x 4KB (v0..v3)
  float* norms         = (float*)(ws + 92 * MB + 90112);   // 64B
  float* dcoef         = (float*)(ws + 92 * MB + 90176);   // 64B

  // G partials live in the (not yet written) y region of d_out: 16 x 4MB = 64MB
  float* P = y_out;

  // 1) LN -> xn ; transpose -> xnT ; weight -> bf16 (+ zero colsumsq, v0 init)
  ln_kernel<<<16384, 256, 0, stream>>>(x, gamma, beta, xn);
  transpose_kernel<<<dim3(256, 16), 256, 0, stream>>>(xn, xnT, 16384, 1024);
  cvt_kernel<<<1024, 256, 0, stream>>>(weight, wb, colsumsq, vpow, norms);

  // 2) G = xnT @ xnT^T symmetric: upper 36 tiles, K=16384 split-16 -> P
  //    flat 576 grid, XCD-slab mapping (mode 5); 8-wave DEPTH=4 ring
  gemm_bt_kernel<128, 2, 4, 4, 1><<<dim3(576), 512, 0, stream>>>(
      xnT, xnT, nullptr, nullptr, nullptr, nullptr, P, nullptr, nullptr,
      16384, 1024, 5, 0.f, 0.f, 0.f);
  reduce_g_kernel<<<dim3(16, 36), 256, 0, stream>>>(P, Gb, gdiag);

  // 3) t_out = 0.9*trace + (1/32)*(W@G)  (diag of G corrected in f32)
  gemm_bt_kernel<64, 4, 2, 8, 2><<<dim3(16, 16), 512, 0, stream>>>(
      wb, Gb, trace, weight, gdiag, nullptr, t_out, nullptr, nullptr,
      1024, 1024, 3, 0.f, 0.f, 0.f);

  // 4) y = xn @ W^T, XCD-swizzled flat grid; 8-wave DEPTH=4 ring
  gemm_bt_kernel<128, 2, 4, 4, 1><<<dim3(1024), 512, 0, stream>>>(
      xn, wb, nullptr, nullptr, nullptr, nullptr, y_out, nullptr, nullptr,
      1024, 1024, 6, 0.f, 0.f, 0.f);

  // 5) w-build (+atomic col norms) -> fused X0 (f32+bf16+bf16^T)
  wbuild_kernel<<<16, 256, 0, stream>>>(weight, t_out, wbuf, colsumsq);
  x0t_kernel<<<dim3(16, 16), 256, 0, stream>>>(wbuf, colsumsq, Xf0, Xb0, XbT0);

  // 6) A0 = X0^T X0 (f32 + bf16) ; power iteration for sigma_max
  gemm_bt_kernel<64, 4, 2, 8, 2><<<dim3(16, 16), 512, 0, stream>>>(
      XbT0, XbT0, nullptr, nullptr, nullptr, nullptr, Af, Ab, nullptr,
      1024, 1024, 0, 0.f, 0.f, 0.f);
  matvec_kernel<<<64, 256, 0, stream>>>(Af, vpow, vpow + 1024, norms + 0);
  matvec_kernel<<<64, 256, 0, stream>>>(Af, vpow + 1024, vpow + 2048, norms + 1);
  matvec_kernel<<<64, 256, 0, stream>>>(Af, vpow + 2048, vpow + 3072, norms + 2);
  coefq_kernel<<<1, 1, 0, stream>>>(norms, dcoef);

  const float QA = 3.4445f, QB = -4.7750f, QC = 2.0315f;
  float* Xf[2] = {Xf0, Xf1};
  unsigned short* Xb[2] = {Xb0, Xb1};
  unsigned short* XbT[2] = {XbT0, XbT1};
  int cur = 0;

  // quintic 1 (scaled via device coeffs): B = dc0*I + dc1*A0 + dc2*A0^2 ; X <- X0@B
  gemm_bt_kernel<64, 4, 2, 8, 2><<<dim3(16, 16), 512, 0, stream>>>(
      Ab, Ab, Af, nullptr, nullptr, dcoef, nullptr, Rb, nullptr,
      1024, 1024, 2, 0.f, 0.f, 0.f);
  gemm_bt_kernel<64, 4, 2, 8, 2><<<dim3(16, 16), 512, 0, stream>>>(
      Xb[cur], Rb, nullptr, nullptr, nullptr, nullptr,
      Xf[cur ^ 1], Xb[cur ^ 1], XbT[cur ^ 1], 1024, 1024, 0, 0.f, 0.f, 0.f);
  cur ^= 1;

  // quintic 2,3: A = X^T X ; B = QA*I + QB*A + QC*A^2 ; X <- X@B
  for (int q = 0; q < 2; q++) {
    gemm_bt_kernel<64, 4, 2, 8, 2><<<dim3(16, 16), 512, 0, stream>>>(
        XbT[cur], XbT[cur], nullptr, nullptr, nullptr, nullptr, Af, Ab, nullptr,
        1024, 1024, 0, 0.f, 0.f, 0.f);
    gemm_bt_kernel<64, 4, 2, 8, 2><<<dim3(16, 16), 512, 0, stream>>>(
        Ab, Ab, Af, nullptr, nullptr, nullptr, nullptr, Rb, nullptr,
        1024, 1024, 1, QA, QB, QC);
    gemm_bt_kernel<64, 4, 2, 8, 2><<<dim3(16, 16), 512, 0, stream>>>(
        Xb[cur], Rb, nullptr, nullptr, nullptr, nullptr,
        Xf[cur ^ 1], Xb[cur ^ 1], XbT[cur ^ 1], 1024, 1024, 0, 0.f, 0.f, 0.f);
    cur ^= 1;
  }

  // cubic 1..3: R = 0.5*(I - X^T X) ; X <- X + X@R
  for (int t = 0; t < 3; t++) {
    gemm_bt_kernel<64, 4, 2, 8, 2><<<dim3(16, 16), 512, 0, stream>>>(
        XbT[cur], XbT[cur], nullptr, nullptr, nullptr, nullptr, nullptr, Rb,
        nullptr, 1024, 1024, 1, 0.5f, 0.f, -0.5f);
    bool last = (t == 2);
    gemm_bt_kernel<64, 4, 2, 8, 2><<<dim3(16, 16), 512, 0, stream>>>(
        Xb[cur], Rb, Xf[cur], nullptr, nullptr, nullptr,
        last ? w_out : Xf[cur ^ 1],
        last ? (unsigned short*)nullptr : Xb[cur ^ 1],
        last ? (unsigned short*)nullptr : XbT[cur ^ 1],
        1024, 1024, 0, 0.f, 0.f, 0.f);
    cur ^= 1;
  }
}

// Round 8
// 311.777 us; speedup vs baseline: 1.0681x; 1.0681x over previous
//
#include <hip/hip_runtime.h>

// EfficientHebbian on MI355X (gfx950) — round 11.
// r10 falsified deep-ring for BM=128 (2nd time) -> revert big GEMMs to
// r9-proven DEPTH=2 / 4-wave / 256thr / 64KB (2 blk/CU). New this round:
// lnt_kernel fuses LN + transpose (writes xn AND xnT, kperm'd; saves 32MB
// re-read + 1 launch); coefq folded into the mode-2 GEMM epilogue.
// kperm'd operand storage throughout (bank-conflict-free ds_read_b128).

typedef short short4v __attribute__((ext_vector_type(4)));
typedef short short8v __attribute__((ext_vector_type(8)));
typedef unsigned short ushort4v __attribute__((ext_vector_type(4)));
typedef unsigned short ushort8v __attribute__((ext_vector_type(8)));
typedef float f32x4 __attribute__((ext_vector_type(4)));

__device__ __forceinline__ unsigned short f2bf(float f) {
  union { float f; unsigned u; } v; v.f = f;
  unsigned r = 0x7fffu + ((v.u >> 16) & 1u);
  return (unsigned short)((v.u + r) >> 16);
}

// k-permutation within a 64-element group: natural k -> stored position.
// Stored 16B chunk c=(ks*4+g) holds natural {ks*32+g*4+[0,4), ks*32+g*4+16+[0,4)}
// = exactly one mfma_16x16x32 bf16 fragment per lane. Preserves low 2 bits.
__device__ __forceinline__ int kperm(int t) {
  return (t & 32) + ((t >> 2) & 3) * 8 + ((t >> 4) & 1) * 4 + (t & 3);
}

__device__ __forceinline__ void gload_lds16(const void* g, void* l) {
  __builtin_amdgcn_global_load_lds(
      (const __attribute__((address_space(1))) void*)g,
      (__attribute__((address_space(3))) void*)l, 16, 0, 0);
}

// counted vmcnt wait; "memory" clobber = compiler fence for LDS/VMEM motion
__device__ __forceinline__ void waitvm(int n) {
  switch (n) {
    case 0: asm volatile("s_waitcnt vmcnt(0)" ::: "memory"); break;
    case 2: asm volatile("s_waitcnt vmcnt(2)" ::: "memory"); break;
    case 4: asm volatile("s_waitcnt vmcnt(4)" ::: "memory"); break;
    case 6: asm volatile("s_waitcnt vmcnt(6)" ::: "memory"); break;
    case 8: asm volatile("s_waitcnt vmcnt(8)" ::: "memory"); break;
    case 10: asm volatile("s_waitcnt vmcnt(10)" ::: "memory"); break;
    case 12: asm volatile("s_waitcnt vmcnt(12)" ::: "memory"); break;
    default: asm volatile("s_waitcnt vmcnt(0)" ::: "memory"); break;
  }
}

// ---- fused LayerNorm + transpose: x[16384][1024] f32 -> xn (kperm'd rows)
// ---- and xnT[1024][16384] (kperm'd k-dim). 256 blocks x 512 thr; each block
// ---- owns 64 rows. LDS tile LDT=1025 (odd stride -> ~2-way banks, free).
__global__ void __launch_bounds__(512) lnt_kernel(
    const float* __restrict__ x, const float* __restrict__ gamma,
    const float* __restrict__ beta, unsigned short* __restrict__ xn,
    unsigned short* __restrict__ xnT) {
  constexpr int LDT = 1025;
  __shared__ unsigned short tb[64 * LDT];  // 131200 B
  const int t = threadIdx.x, lane = t & 63, grp = t >> 6;  // 8 groups x 8 rows
  const int r0 = blockIdx.x * 64;
  f32x4 g4[4], b4[4];
#pragma unroll
  for (int q = 0; q < 4; q++) {
    g4[q] = *(const f32x4*)(gamma + q * 256 + lane * 4);
    b4[q] = *(const f32x4*)(beta + q * 256 + lane * 4);
  }
  const int kbase = (lane * 4 & ~63) + kperm(lane * 4 & 63);
  for (int i = 0; i < 8; i++) {
    int lr = grp * 8 + i;
    const float* xr = x + (size_t)(r0 + lr) * 1024;
    f32x4 v[4];
#pragma unroll
    for (int q = 0; q < 4; q++) v[q] = *(const f32x4*)(xr + q * 256 + lane * 4);
    float s = 0.f;
#pragma unroll
    for (int q = 0; q < 4; q++) s += v[q][0] + v[q][1] + v[q][2] + v[q][3];
    for (int m = 32; m; m >>= 1) s += __shfl_xor(s, m);
    float mu = s * (1.0f / 1024.0f);
    float qs = 0.f;
#pragma unroll
    for (int q = 0; q < 4; q++)
#pragma unroll
      for (int j = 0; j < 4; j++) { float d = v[q][j] - mu; qs += d * d; }
    for (int m = 32; m; m >>= 1) qs += __shfl_xor(qs, m);
    float rs = rsqrtf(qs * (1.0f / 1024.0f) + 1e-5f);
    unsigned short* xrow = xn + (size_t)(r0 + lr) * 1024;
    unsigned short* trow = tb + lr * LDT;
#pragma unroll
    for (int q = 0; q < 4; q++) {
      ushort4v o;
#pragma unroll
      for (int j = 0; j < 4; j++) {
        o[j] = f2bf((v[q][j] - mu) * rs * g4[q][j] + b4[q][j]);
        trow[q * 256 + lane * 4 + j] = o[j];   // natural layout in LDS
      }
      *(ushort4v*)(xrow + q * 256 + kbase) = o;  // kperm'd row store
    }
  }
  __syncthreads();
  // phase 2: write xnT[c][r0..r0+63], kperm'd within the 64-token group
  const int k4 = (t & 15) * 4;
  const int kp = kperm(k4);
  for (int it = 0; it < 32; ++it) {
    int c = (t >> 4) + 32 * it;
    ushort4v w;
#pragma unroll
    for (int j = 0; j < 4; j++) w[j] = tb[(k4 + j) * LDT + c];
    *(ushort4v*)(xnT + (size_t)c * 16384 + r0 + kp) = w;
  }
}

// ------- f32 -> bf16 convert (kperm'd); block 0 zeroes colsumsq;
// ------- block 1 does power-iteration v0 init + zeroes norms ---------------
__global__ void __launch_bounds__(256) cvt_kernel(
    const float* __restrict__ in, unsigned short* __restrict__ out,
    float* __restrict__ zbuf, float* __restrict__ v0,
    float* __restrict__ norms) {
  if (blockIdx.x == 0) {
    f32x4 z = (f32x4){0.f, 0.f, 0.f, 0.f};
    ((f32x4*)zbuf)[threadIdx.x] = z;
  } else if (blockIdx.x == 1) {
    int t = threadIdx.x;
    for (int q = 0; q < 4; q++) {
      int i = t * 4 + q;
      unsigned h = (unsigned)i * 2654435761u;
      v0[i] = ((h >> 16) & 1u) ? 1.f : -1.f;
    }
    if (t < 4) norms[t] = 0.f;
  }
  size_t e = ((size_t)blockIdx.x * 256 + threadIdx.x) * 4;
  f32x4 v = *(const f32x4*)(in + e);
  ushort4v o;
  for (int k = 0; k < 4; k++) o[k] = f2bf(v[k]);
  int col = (int)(e & 1023);
  size_t sp = (e & ~(size_t)1023) + (col & ~63) + kperm(col & 63);
  *(ushort4v*)(out + sp) = o;
}

// ---------------- NT GEMM: C[M][N] = A[M][K] @ B[N][K]^T ----------------
// Operands stored kperm'd; fragment read = single ds_read_b128, conflict-free.
// BM x BM tile, BK=64, NK=16 K-steps, WM x WN waves. DEPTH-buffer ring,
// raw s_barrier + counted vmcnt, U tiles per barrier window.
// modes: 0: v=acc (+addF) ; 1: c0*I+c1*addF+c2*acc
//        2: quintic-1: coeffs computed inline from norms (dcoef=norms ptr,
//           c0..c2 = QA,QB,QC): s from power-iter, dcK = cK/s^(2K+1)
//        3: 0.9*addF + (1/32)*(acc + addF2*dvec[c])
//        5: symmetric-upper partial, XCD-slab map (flat 576 grid)
//        6: mode 0 with flat-grid XCD swizzle (M=128,N=8 tiles)
template <int BM, int WM, int WN, int DEPTH, int U>
__global__ void __launch_bounds__(WM * WN * 64, (WM * WN) / 2) gemm_bt_kernel(
    const unsigned short* __restrict__ A, const unsigned short* __restrict__ B,
    const float* __restrict__ addF, const float* __restrict__ addF2,
    const float* __restrict__ dvec, const float* __restrict__ dcoef,
    float* __restrict__ outF, unsigned short* __restrict__ outB,
    unsigned short* __restrict__ outBT,
    int ldk, int Kseg, int mode, float c0, float c1, float c2) {
  constexpr int WAVES = WM * WN;
  constexpr int NT = WAVES * 64;
  constexpr int FMm = BM / (16 * WM);
  constexpr int FMn = BM / (16 * WN);
  constexpr int CPW = BM / (8 * WAVES);  // 1KB chunks per wave per operand
  constexpr int L = 2 * CPW;             // vmem loads per wave per stage
  constexpr int BUFS = 2 * BM * 64;      // shorts per buffer (A then B)
  constexpr int NK = 16;                 // Kseg == 1024 always
  constexpr int NG = NK / U;
  __shared__ __align__(16) unsigned short lds[DEPTH * BUFS];
  const int tid = threadIdx.x, lane = tid & 63, wv = tid >> 6;
  const int wm = wv / WN, wn = wv % WN;

  int m0, n0, kb = 0, zseg = 0;
  if (mode == 5) {
    int id = blockIdx.x;
    int c = id & 7, s = id >> 3;
    zseg = c * 2 + (s >= 36 ? 1 : 0);
    int tt = (s >= 36) ? s - 36 : s;
    int ti = 0;
    while (tt >= 8 - ti) { tt -= 8 - ti; ++ti; }
    m0 = ti * BM; n0 = (ti + tt) * BM;
    kb = zseg * Kseg;
  } else if (mode == 6) {
    int l = blockIdx.x;
    int c = l & 7, s = l >> 3;
    m0 = (c * 16 + (s >> 3)) * BM;
    n0 = (s & 7) * BM;
  } else {
    m0 = blockIdx.x * BM; n0 = blockIdx.y * BM;
  }

  const int srow = lane >> 3;
  const int skoff = 8 * ((lane & 7) ^ srow);  // pre-swizzled global k-offset

  f32x4 acc[FMm][FMn];
  for (int a = 0; a < FMm; a++)
    for (int b = 0; b < FMn; b++) acc[a][b] = (f32x4){0.f, 0.f, 0.f, 0.f};

  auto stage = [&](int buf, int kk) {
#pragma unroll
    for (int ci = 0; ci < CPW; ci++) {
      int ch = wv * CPW + ci;
      const unsigned short* ga = A + (size_t)(m0 + 8 * ch + srow) * ldk + kk + skoff;
      const unsigned short* gb = B + (size_t)(n0 + 8 * ch + srow) * ldk + kk + skoff;
      char* lb = (char*)(lds + buf * BUFS);
      gload_lds16(ga, lb + ch * 1024);
      gload_lds16(gb, lb + BM * 128 + ch * 1024);
    }
  };

  // prologue: DEPTH-U stages in flight
#pragma unroll
  for (int d = 0; d < DEPTH - U; ++d) stage(d, kb + (d << 6));

#pragma unroll
  for (int g = 0; g < NG; ++g) {
    int done = U * g + U;                       // tiles that must be complete
    int issued = DEPTH - U + U * g;
    if (issued > NK) issued = NK;
    int ahead = issued - done;                  // stages allowed in flight
    waitvm(ahead * L);
    __builtin_amdgcn_s_barrier();
#pragma unroll
    for (int u = 0; u < U; ++u) {
      int ts = U * g + (DEPTH - U) + u;
      if (ts < NK) stage(ts % DEPTH, kb + (ts << 6));
    }

    const int g16 = lane >> 4;
#pragma unroll
    for (int u = 0; u < U; ++u) {
      const unsigned short* As = lds + ((U * g + u) % DEPTH) * BUFS;
      const unsigned short* Bs = As + BM * 64;
#pragma unroll
      for (int ks = 0; ks < 2; ks++) {
        short8v af[FMm], bfr[FMn];
        const int slot = (ks * 4 + g16) * 16;   // 16B chunk = full fragment
#pragma unroll
        for (int fm = 0; fm < FMm; fm++) {
          int row = wm * (BM / WM) + fm * 16 + (lane & 15);
          int swz = (row & 7) << 4;
          af[fm] = *(const short8v*)((const char*)As + row * 128 + (slot ^ swz));
        }
#pragma unroll
        for (int fn = 0; fn < FMn; fn++) {
          int row = wn * (BM / WN) + fn * 16 + (lane & 15);
          int swz = (row & 7) << 4;
          bfr[fn] = *(const short8v*)((const char*)Bs + row * 128 + (slot ^ swz));
        }
#pragma unroll
        for (int fm = 0; fm < FMm; fm++)
#pragma unroll
          for (int fn = 0; fn < FMn; fn++)
            acc[fm][fn] = __builtin_amdgcn_mfma_f32_16x16x32_bf16(
                af[fm], bfr[fn], acc[fm][fn], 0, 0, 0);
      }
    }
  }

  float* of = outF;
  if (mode == 5 && of) of += ((size_t)zseg << 20);
  float dc0 = 0.f, dc1 = 0.f, dc2 = 0.f;
  if (mode == 2) {
    // inline coefq: dcoef points at norms[] from power iteration
    float n1 = fmaxf(dcoef[1], 1e-30f), n2 = fmaxf(dcoef[2], 1e-30f);
    float lam = sqrtf(n2 / n1);
    float s = sqrtf(fmaxf(lam, 1e-8f)) / 0.95f;
    s = fmaxf(s, 1e-3f);
    float s2 = s * s;
    dc0 = c0 / s;
    dc1 = c1 / (s * s2);
    dc2 = c2 / (s * s2 * s2);
  }

#pragma unroll
  for (int fm = 0; fm < FMm; fm++) {
    int r0 = m0 + wm * (BM / WM) + fm * 16 + (lane >> 4) * 4;
#pragma unroll
    for (int fn = 0; fn < FMn; fn++) {
      int c = n0 + wn * (BM / WN) + fn * 16 + (lane & 15);
      int cperm = (c & ~63) + kperm(c & 63);    // stored col for bf16 out
#pragma unroll
      for (int j = 0; j < 4; j++) {
        int r = r0 + j;
        size_t off = (size_t)r * 1024 + c;
        float v = acc[fm][fn][j];
        if (mode == 0 || mode == 6) {
          if (addF) v += addF[off];
        } else if (mode == 1) {
          v = c0 * (r == c ? 1.f : 0.f) + (addF ? c1 * addF[off] : 0.f) + c2 * v;
        } else if (mode == 2) {
          v = dc0 * (r == c ? 1.f : 0.f) + dc1 * addF[off] + dc2 * v;
        } else if (mode == 3) {
          v = 0.9f * addF[off] + 0.03125f * (v + addF2[off] * dvec[c]);
        }
        if (of) of[off] = v;
        if (outB) outB[(size_t)r * 1024 + cperm] = f2bf(v);
        acc[fm][fn][j] = v;
      }
    }
  }

  // optional transposed bf16 output (BM=64 NS X-updates only), kperm'd k-dim
  if (outBT) {
    constexpr int LDT = BM + 1;
    __syncthreads();
#pragma unroll
    for (int fm = 0; fm < FMm; fm++) {
      int lr0 = wm * (BM / WM) + fm * 16 + (lane >> 4) * 4;
#pragma unroll
      for (int fn = 0; fn < FMn; fn++) {
        int lc = wn * (BM / WN) + fn * 16 + (lane & 15);
#pragma unroll
        for (int j = 0; j < 4; j++)
          lds[(lr0 + j) * LDT + lc] = f2bf(acc[fm][fn][j]);
      }
    }
    __syncthreads();
    for (int e = tid * 8; e < BM * BM; e += NT * 8) {
      int orr = e / BM;          // output row = col of tile
      int oc = e % BM;           // natural k offset (row of tile), mult of 8
      ushort4v w0, w1;
#pragma unroll
      for (int d = 0; d < 4; d++) {
        w0[d] = lds[(oc + d) * LDT + orr];
        w1[d] = lds[(oc + 4 + d) * LDT + orr];
      }
      unsigned short* orow = outBT + (size_t)(n0 + orr) * 1024 + m0;
      *(ushort4v*)(orow + kperm(oc & 63)) = w0;
      *(ushort4v*)(orow + kperm((oc + 4) & 63)) = w1;
    }
  }
}

// ---- reduce G: sum 16 partials over upper 128^2 tiles -> Gb bf16 (kperm'd),
// mirror lower triangle, diag zeroed + gdiag. grid: dim3(16, 36 tiles).
__global__ void __launch_bounds__(256) reduce_g_kernel(
    const float* __restrict__ P, unsigned short* __restrict__ Gb,
    float* __restrict__ gdiag) {
  int tt = blockIdx.y, ti = 0;
  while (tt >= 8 - ti) { tt -= 8 - ti; ++ti; }
  const int tj = ti + tt;
  const int eloc = (blockIdx.x * 256 + threadIdx.x) * 4;
  const int lr = eloc >> 7, lc = eloc & 127;
  const int r = ti * 128 + lr, c0 = tj * 128 + lc;
  const size_t off = (size_t)r * 1024 + c0;
  f32x4 s = *(const f32x4*)(P + off);
#pragma unroll
  for (int z = 1; z < 16; z++)
    s += *(const f32x4*)(P + ((size_t)z << 20) + off);
  ushort4v o;
  const int rperm = (r & ~63) + kperm(r & 63);
#pragma unroll
  for (int q = 0; q < 4; q++) {
    int c = c0 + q;
    unsigned short b = f2bf(s[q]);
    if (ti == tj && c == r) { gdiag[r] = s[q]; o[q] = 0; }
    else o[q] = b;
    if (ti != tj) Gb[(size_t)c * 1024 + rperm] = b;  // mirror (kperm'd col)
  }
  *(ushort4v*)(Gb + (size_t)r * 1024 + (c0 & ~63) + kperm(c0 & 63)) = o;
}

// --- w = weight + 0.01*clip(trace,-1,1); atomic per-column sumsq -------------
__global__ void __launch_bounds__(256) wbuild_kernel(
    const float* __restrict__ weight, const float* __restrict__ tout,
    float* __restrict__ w, float* __restrict__ colsumsq) {
  int t = threadIdx.x, blk = blockIdx.x;
  float cs[4] = {0.f, 0.f, 0.f, 0.f};
  for (int r = 0; r < 64; r++) {
    size_t row = (size_t)blk * 64 + r;
    for (int cc = 0; cc < 4; cc++) {
      size_t idx = row * 1024 + cc * 256 + t;
      float u = tout[idx];
      u = fminf(fmaxf(u, -1.f), 1.f);
      float wv = weight[idx] + 0.01f * u;
      w[idx] = wv;
      cs[cc] += wv * wv;
    }
  }
  for (int cc = 0; cc < 4; cc++) atomicAdd(&colsumsq[cc * 256 + t], cs[cc]);
}

// --- X0 = w / max(colnorm,1e-3): writes Xf (f32), Xb (bf16 kperm'd),
// XbT (bf16 kperm'd k-dim). tile-based 64x64.
__global__ void __launch_bounds__(256) x0t_kernel(
    const float* __restrict__ w, const float* __restrict__ colsumsq,
    float* __restrict__ X, unsigned short* __restrict__ Xb,
    unsigned short* __restrict__ XbT) {
  __shared__ unsigned short tb[64][65];
  const int t = threadIdx.x;
  const int r0 = blockIdx.x * 64, c0 = blockIdx.y * 64;
#pragma unroll
  for (int p = 0; p < 2; p++) {
    int lr = p * 32 + (t >> 3);
    int lc = (t & 7) * 8;  // natural col offset
    size_t base = (size_t)(r0 + lr) * 1024 + c0 + lc;
    f32x4 w0 = *(const f32x4*)(w + base);
    f32x4 w1 = *(const f32x4*)(w + base + 4);
    f32x4 s0 = *(const f32x4*)(colsumsq + c0 + lc);
    f32x4 s1 = *(const f32x4*)(colsumsq + c0 + lc + 4);
    f32x4 x0o, x1o; ushort4v xb0, xb1;
#pragma unroll
    for (int d = 0; d < 4; d++) {
      x0o[d] = w0[d] / fmaxf(sqrtf(s0[d]), 1e-3f);
      x1o[d] = w1[d] / fmaxf(sqrtf(s1[d]), 1e-3f);
      xb0[d] = f2bf(x0o[d]); xb1[d] = f2bf(x1o[d]);
      tb[lr][lc + d] = xb0[d]; tb[lr][lc + 4 + d] = xb1[d];
    }
    *(f32x4*)(X + base) = x0o;
    *(f32x4*)(X + base + 4) = x1o;
    unsigned short* xrow = Xb + (size_t)(r0 + lr) * 1024 + c0;
    *(ushort4v*)(xrow + kperm(lc)) = xb0;
    *(ushort4v*)(xrow + kperm(lc + 4)) = xb1;
  }
  __syncthreads();
#pragma unroll
  for (int p = 0; p < 2; p++) {
    int orr = p * 32 + (t >> 3);
    int oc = (t & 7) * 8;  // natural row offset (k-dim of XbT)
    ushort4v w0, w1;
#pragma unroll
    for (int d = 0; d < 4; d++) { w0[d] = tb[oc + d][orr]; w1[d] = tb[oc + 4 + d][orr]; }
    unsigned short* orow = XbT + (size_t)(c0 + orr) * 1024 + r0;
    *(ushort4v*)(orow + kperm(oc)) = w0;
    *(ushort4v*)(orow + kperm(oc + 4)) = w1;
  }
}

// ---------------- matvec: vout = A vin (A f32 1024x1024); ||vout||^2 += norm --
__global__ void __launch_bounds__(256) matvec_kernel(
    const float* __restrict__ A, const float* __restrict__ vin,
    float* __restrict__ vout, float* __restrict__ normsq) {
  __shared__ float red[4];
  int t = threadIdx.x;
  int r0 = blockIdx.x * 16;
  f32x4 vv = *(const f32x4*)(vin + t * 4);
  float sq = 0.f;
  for (int r = 0; r < 16; r++) {
    f32x4 a = *(const f32x4*)(A + (size_t)(r0 + r) * 1024 + t * 4);
    float d = a[0] * vv[0] + a[1] * vv[1] + a[2] * vv[2] + a[3] * vv[3];
    for (int m = 32; m; m >>= 1) d += __shfl_xor(d, m);
    if ((t & 63) == 0) red[t >> 6] = d;
    __syncthreads();
    if (t == 0) {
      float s = red[0] + red[1] + red[2] + red[3];
      vout[r0 + r] = s;
      sq += s * s;
    }
    __syncthreads();
  }
  if (t == 0) atomicAdd(normsq, sq);
}

extern "C" void kernel_launch(void* const* d_in, const int* in_sizes, int n_in,
                              void* d_out, int out_size, void* d_ws, size_t ws_size,
                              hipStream_t stream) {
  const float* x      = (const float*)d_in[0];
  const float* weight = (const float*)d_in[1];
  const float* gamma  = (const float*)d_in[2];
  const float* beta   = (const float*)d_in[3];
  const float* trace  = (const float*)d_in[4];

  float* y_out = (float*)d_out;                  // [16384,1024]
  float* w_out = y_out + (size_t)16777216;       // [1024,1024]
  float* t_out = w_out + (size_t)1048576;        // [1024,1024]

  const size_t MB = 1048576;
  char* ws = (char*)d_ws;
  unsigned short* xn   = (unsigned short*)(ws);            // 32MB
  unsigned short* xnT  = (unsigned short*)(ws + 32 * MB);  // 32MB
  float* Xf0           = (float*)(ws + 64 * MB);           // 4MB
  float* Xf1           = (float*)(ws + 68 * MB);           // 4MB
  float* wbuf          = (float*)(ws + 72 * MB);           // 4MB (reused as Af)
  float* Af            = (float*)(ws + 72 * MB);           //   alias (wbuf dead)
  unsigned short* Xb0  = (unsigned short*)(ws + 76 * MB);  // 2MB
  unsigned short* Xb1  = (unsigned short*)(ws + 78 * MB);  // 2MB
  unsigned short* XbT0 = (unsigned short*)(ws + 80 * MB);  // 2MB
  unsigned short* XbT1 = (unsigned short*)(ws + 82 * MB);  // 2MB
  unsigned short* Ab   = (unsigned short*)(ws + 84 * MB);  // 2MB
  unsigned short* Rb   = (unsigned short*)(ws + 86 * MB);  // 2MB (also quintic B)
  unsigned short* Gb   = (unsigned short*)(ws + 88 * MB);  // 2MB
  unsigned short* wb   = (unsigned short*)(ws + 90 * MB);  // 2MB
  float* colsumsq      = (float*)(ws + 92 * MB);           // 4KB
  float* gdiag         = (float*)(ws + 92 * MB + 69632);   // 4KB
  float* vpow          = (float*)(ws + 92 * MB + 73728);   // 4 x 4KB (v0..v3)
  float* norms         = (float*)(ws + 92 * MB + 90112);   // 64B

  // G partials live in the (not yet written) y region of d_out: 16 x 4MB = 64MB
  float* P = y_out;

  // 1) fused LN+transpose -> xn, xnT ; weight -> bf16 (+ zero colsumsq, v0)
  lnt_kernel<<<256, 512, 0, stream>>>(x, gamma, beta, xn, xnT);
  cvt_kernel<<<1024, 256, 0, stream>>>(weight, wb, colsumsq, vpow, norms);

  // 2) G = xnT @ xnT^T symmetric: upper 36 tiles, K=16384 split-16 -> P
  //    flat 576 grid, XCD-slab mapping (mode 5); r9-proven 4-wave DEPTH=2
  gemm_bt_kernel<128, 2, 2, 2, 1><<<dim3(576), 256, 0, stream>>>(
      xnT, xnT, nullptr, nullptr, nullptr, nullptr, P, nullptr, nullptr,
      16384, 1024, 5, 0.f, 0.f, 0.f);
  reduce_g_kernel<<<dim3(16, 36), 256, 0, stream>>>(P, Gb, gdiag);

  // 3) t_out = 0.9*trace + (1/32)*(W@G)  (diag of G corrected in f32)
  gemm_bt_kernel<64, 4, 2, 8, 2><<<dim3(16, 16), 512, 0, stream>>>(
      wb, Gb, trace, weight, gdiag, nullptr, t_out, nullptr, nullptr,
      1024, 1024, 3, 0.f, 0.f, 0.f);

  // 4) y = xn @ W^T, XCD-swizzled flat grid; r9-proven 4-wave DEPTH=2
  gemm_bt_kernel<128, 2, 2, 2, 1><<<dim3(1024), 256, 0, stream>>>(
      xn, wb, nullptr, nullptr, nullptr, nullptr, y_out, nullptr, nullptr,
      1024, 1024, 6, 0.f, 0.f, 0.f);

  // 5) w-build (+atomic col norms) -> fused X0 (f32+bf16+bf16^T)
  wbuild_kernel<<<16, 256, 0, stream>>>(weight, t_out, wbuf, colsumsq);
  x0t_kernel<<<dim3(16, 16), 256, 0, stream>>>(wbuf, colsumsq, Xf0, Xb0, XbT0);

  // 6) A0 = X0^T X0 (f32 + bf16) ; power iteration for sigma_max
  gemm_bt_kernel<64, 4, 2, 8, 2><<<dim3(16, 16), 512, 0, stream>>>(
      XbT0, XbT0, nullptr, nullptr, nullptr, nullptr, Af, Ab, nullptr,
      1024, 1024, 0, 0.f, 0.f, 0.f);
  matvec_kernel<<<64, 256, 0, stream>>>(Af, vpow, vpow + 1024, norms + 0);
  matvec_kernel<<<64, 256, 0, stream>>>(Af, vpow + 1024, vpow + 2048, norms + 1);
  matvec_kernel<<<64, 256, 0, stream>>>(Af, vpow + 2048, vpow + 3072, norms + 2);

  const float QA = 3.4445f, QB = -4.7750f, QC = 2.0315f;
  float* Xf[2] = {Xf0, Xf1};
  unsigned short* Xb[2] = {Xb0, Xb1};
  unsigned short* XbT[2] = {XbT0, XbT1};
  int cur = 0;

  // quintic 1: B = dc0*I + dc1*A0 + dc2*A0^2 (coeffs inline from norms);
  // X <- X0@B
  gemm_bt_kernel<64, 4, 2, 8, 2><<<dim3(16, 16), 512, 0, stream>>>(
      Ab, Ab, Af, nullptr, nullptr, norms, nullptr, Rb, nullptr,
      1024, 1024, 2, QA, QB, QC);
  gemm_bt_kernel<64, 4, 2, 8, 2><<<dim3(16, 16), 512, 0, stream>>>(
      Xb[cur], Rb, nullptr, nullptr, nullptr, nullptr,
      Xf[cur ^ 1], Xb[cur ^ 1], XbT[cur ^ 1], 1024, 1024, 0, 0.f, 0.f, 0.f);
  cur ^= 1;

  // quintic 2,3: A = X^T X ; B = QA*I + QB*A + QC*A^2 ; X <- X@B
  for (int q = 0; q < 2; q++) {
    gemm_bt_kernel<64, 4, 2, 8, 2><<<dim3(16, 16), 512, 0, stream>>>(
        XbT[cur], XbT[cur], nullptr, nullptr, nullptr, nullptr, Af, Ab, nullptr,
        1024, 1024, 0, 0.f, 0.f, 0.f);
    gemm_bt_kernel<64, 4, 2, 8, 2><<<dim3(16, 16), 512, 0, stream>>>(
        Ab, Ab, Af, nullptr, nullptr, nullptr, nullptr, Rb, nullptr,
        1024, 1024, 1, QA, QB, QC);
    gemm_bt_kernel<64, 4, 2, 8, 2><<<dim3(16, 16), 512, 0, stream>>>(
        Xb[cur], Rb, nullptr, nullptr, nullptr, nullptr,
        Xf[cur ^ 1], Xb[cur ^ 1], XbT[cur ^ 1], 1024, 1024, 0, 0.f, 0.f, 0.f);
    cur ^= 1;
  }

  // cubic 1..3: R = 0.5*(I - X^T X) ; X <- X + X@R
  for (int t = 0; t < 3; t++) {
    gemm_bt_kernel<64, 4, 2, 8, 2><<<dim3(16, 16), 512, 0, stream>>>(
        XbT[cur], XbT[cur], nullptr, nullptr, nullptr, nullptr, nullptr, Rb,
        nullptr, 1024, 1024, 1, 0.5f, 0.f, -0.5f);
    bool last = (t == 2);
    gemm_bt_kernel<64, 4, 2, 8, 2><<<dim3(16, 16), 512, 0, stream>>>(
        Xb[cur], Rb, Xf[cur], nullptr, nullptr, nullptr,
        last ? w_out : Xf[cur ^ 1],
        last ? (unsigned short*)nullptr : Xb[cur ^ 1],
        last ? (unsigned short*)nullptr : XbT[cur ^ 1],
        1024, 1024, 0, 0.f, 0.f, 0.f);
    cur ^= 1;
  }
}